// Round 2
// baseline (626.625 us; speedup 1.0000x reference)
//
#include <hip/hip_runtime.h>
#include <hip/hip_bf16.h>
#include <math.h>

// ---- problem constants ----
#define DM    1024      // d_model
#define DIP   4384      // d_in_proj
#define NP1   4480      // padded in_proj rows (divisible by 128)
#define DI    2048      // d_inner
#define CD    2304      // conv dim
#define NH    32        // heads
#define HD    64        // head dim
#define DS    128       // d_state
#define CH    256       // chunk
#define NCH   16        // chunks per sequence
#define BSZ   2
#define SEQ   4096
#define NTOK  (BSZ*SEQ) // 8192

typedef __bf16 bf16_t;
typedef __attribute__((ext_vector_type(8))) __bf16 bf16x8;
typedef __attribute__((ext_vector_type(4))) float f32x4;

__device__ __forceinline__ f32x4 mfma16(bf16x8 a, bf16x8 b, f32x4 c) {
    return __builtin_amdgcn_mfma_f32_16x16x32_bf16(a, b, c, 0, 0, 0);
}

// ---------------- converts ----------------
__global__ void k_cvt(const float* __restrict__ in, bf16_t* __restrict__ out, int n) {
    int i = blockIdx.x * 256 + threadIdx.x;
    if (i < n) out[i] = (bf16_t)in[i];
}

__global__ void k_cvt_pad(const float* __restrict__ in, bf16_t* __restrict__ out) {
    int i = blockIdx.x * 256 + threadIdx.x;
    if (i >= NP1 * DM) return;
    int r = i >> 10;  // DM=1024
    out[i] = (r < DIP) ? (bf16_t)in[i] : (bf16_t)0.f;
}

// ---------------- GEMM: C[M x ldc] = A[M x K] * Bt[N x K]^T  (bf16 in, OutT out)
// grid (N/128, M/128), block 256 (4 waves, 2x2 of 64x64)
template <typename OutT>
__global__ __launch_bounds__(256) void k_gemm(const bf16_t* __restrict__ A,
                                              const bf16_t* __restrict__ Bt,
                                              OutT* __restrict__ C, int K, int ldc) {
    __shared__ __align__(16) bf16_t sA[128][40];
    __shared__ __align__(16) bf16_t sB[128][40];
    int tid = threadIdx.x;
    int wave = tid >> 6, lane = tid & 63;
    int l15 = lane & 15, quad = lane >> 4;
    int m0 = blockIdx.y * 128, n0 = blockIdx.x * 128;
    int wm = (wave & 1) * 64, wn = (wave >> 1) * 64;
    f32x4 acc[4][4];
#pragma unroll
    for (int i = 0; i < 4; i++)
#pragma unroll
        for (int j = 0; j < 4; j++) acc[i][j] = (f32x4){0.f, 0.f, 0.f, 0.f};

    int lrow = tid >> 1, lcol = (tid & 1) * 16;
    const bf16_t* Ap = A + (size_t)(m0 + lrow) * K + lcol;
    const bf16_t* Bp = Bt + (size_t)(n0 + lrow) * K + lcol;
    for (int k0 = 0; k0 < K; k0 += 32) {
        *(bf16x8*)&sA[lrow][lcol]     = *(const bf16x8*)(Ap + k0);
        *(bf16x8*)&sA[lrow][lcol + 8] = *(const bf16x8*)(Ap + k0 + 8);
        *(bf16x8*)&sB[lrow][lcol]     = *(const bf16x8*)(Bp + k0);
        *(bf16x8*)&sB[lrow][lcol + 8] = *(const bf16x8*)(Bp + k0 + 8);
        __syncthreads();
        bf16x8 af[4], bg[4];
#pragma unroll
        for (int mt = 0; mt < 4; mt++) af[mt] = *(const bf16x8*)&sA[wm + mt * 16 + l15][quad * 8];
#pragma unroll
        for (int nt = 0; nt < 4; nt++) bg[nt] = *(const bf16x8*)&sB[wn + nt * 16 + l15][quad * 8];
#pragma unroll
        for (int mt = 0; mt < 4; mt++)
#pragma unroll
            for (int nt = 0; nt < 4; nt++)
                acc[mt][nt] = mfma16(af[mt], bg[nt], acc[mt][nt]);
        __syncthreads();
    }
#pragma unroll
    for (int mt = 0; mt < 4; mt++)
#pragma unroll
        for (int nt = 0; nt < 4; nt++)
#pragma unroll
            for (int r = 0; r < 4; r++)
                C[(size_t)(m0 + wm + mt * 16 + quad * 4 + r) * ldc + n0 + wn + nt * 16 + l15] =
                    (OutT)acc[mt][nt][r];
}

// ---------------- dt + softplus + per-chunk cumsum of dt*A ----------------
// grid 1024 = bc*NH + h, 256 threads (q)
__global__ __launch_bounds__(256) void k_dtcum(const float* __restrict__ dtf,
                                               const float* __restrict__ delta_t,
                                               const float* __restrict__ gamma,
                                               const float* __restrict__ dt_bias,
                                               const float* __restrict__ A_log,
                                               float* __restrict__ dtb, float* __restrict__ acum) {
    int blk = blockIdx.x;
    int h = blk & (NH - 1), bc = blk >> 5;
    int q = threadIdx.x;
    size_t tok = (size_t)bc * CH + q;
    float x = dtf[tok * 128 + h] + gamma[h] * delta_t[tok] + dt_bias[h];
    float dt = (x > 20.f) ? x : log1pf(expf(x));
    float Ah = -expf(A_log[h]);
    __shared__ __align__(16) float s[CH];
    s[q] = dt * Ah;
    __syncthreads();
#pragma unroll
    for (int off = 1; off < CH; off <<= 1) {
        float v = (q >= off) ? s[q - off] : 0.f;
        __syncthreads();
        s[q] += v;
        __syncthreads();
    }
    dtb[(size_t)blk * CH + q] = dt;
    acum[(size_t)blk * CH + q] = s[q];
}

// ---------------- causal depthwise conv (4 taps) + bias + silu -> bf16 ----------------
// grid (9, NTOK): ch = bx*256+tid, tok = by
__global__ void k_conv(const bf16_t* __restrict__ zx, const float* __restrict__ cw,
                       const float* __restrict__ cb, bf16_t* __restrict__ xBC) {
    int ch = blockIdx.x * 256 + threadIdx.x;
    int tok = blockIdx.y;
    int l = tok & (SEQ - 1);
    float acc = cb[ch];
#pragma unroll
    for (int t = 0; t < 4; t++) {
        int ll = l - 3 + t;
        if (ll >= 0) acc += (float)zx[(size_t)(tok - 3 + t) * CD + ch] * cw[ch * 4 + t];
    }
    float sv = acc / (1.f + expf(-acc));
    xBC[(size_t)tok * CD + ch] = (bf16_t)sv;
}

// ---------------- transpose + dt fold ----------------
// grid (34, bc): t<32 -> head t: Xt[p][q] = x*dt ; t in {32,33} -> Btr[n][q]
__global__ __launch_bounds__(256) void k_trans(const bf16_t* __restrict__ xBC,
                                               const float* __restrict__ dtb,
                                               bf16_t* __restrict__ Xt, bf16_t* __restrict__ Btr) {
    int t = blockIdx.x, bc = blockIdx.y, tid = threadIdx.x;
    __shared__ __align__(16) bf16_t tile[CH][72];
    __shared__ __align__(16) float sdt[CH];
    int chbase = (t < 32) ? t * 64 : DI + (t - 32) * 64;
#pragma unroll
    for (int pp = 0; pp < 8; pp++) {
        int q = pp * 32 + (tid >> 3), col = (tid & 7) * 8;
        *(bf16x8*)&tile[q][col] = *(const bf16x8*)(xBC + (size_t)(bc * CH + q) * CD + chbase + col);
    }
    if (t < 32) sdt[tid] = dtb[(size_t)(bc * NH + t) * CH + tid];
    __syncthreads();
    int pl = tid >> 2, qg = tid & 3;
#pragma unroll
    for (int c8 = 0; c8 < 8; c8++) {
        int q0 = qg * 64 + c8 * 8;
        bf16x8 v;
        if (t < 32) {
#pragma unroll
            for (int j = 0; j < 8; j++) v[j] = (bf16_t)((float)tile[q0 + j][pl] * sdt[q0 + j]);
            size_t row = (size_t)(bc * NH + t) * 64 + pl;
            *(bf16x8*)(Xt + row * CH + q0) = v;
        } else {
#pragma unroll
            for (int j = 0; j < 8; j++) v[j] = tile[q0 + j][pl];
            size_t row = (size_t)bc * DS + (t - 32) * 64 + pl;
            *(bf16x8*)(Btr + row * CH + q0) = v;
        }
    }
}

// ---------------- per-chunk states: states[p][n] = sum_k Xt[p][k]*decay[k]*Btr[n][k] ----------------
// grid 1024 = bc*NH+h, 4 waves: wave w -> n in [w*32, w*32+32)
__global__ __launch_bounds__(256) void k_states(const bf16_t* __restrict__ Xt,
                                                const bf16_t* __restrict__ Btr,
                                                const float* __restrict__ acum,
                                                float* __restrict__ states) {
    int blk = blockIdx.x;
    int bc = blk >> 5;
    int tid = threadIdx.x, wave = tid >> 6, lane = tid & 63;
    int l15 = lane & 15, quad = lane >> 4;
    __shared__ __align__(16) float sdec[CH];
    {
        size_t base = (size_t)blk * CH;
        float al = acum[base + CH - 1];
        sdec[tid] = expf(al - acum[base + tid]);
    }
    __syncthreads();
    const bf16_t* Xb = Xt + (size_t)blk * 64 * CH;
    const bf16_t* Bb = Btr + (size_t)bc * DS * CH;
    f32x4 acc[4][2];
#pragma unroll
    for (int i = 0; i < 4; i++)
#pragma unroll
        for (int j = 0; j < 2; j++) acc[i][j] = (f32x4){0.f, 0.f, 0.f, 0.f};
#pragma unroll
    for (int ks = 0; ks < 8; ks++) {
        float d0[8];
#pragma unroll
        for (int j = 0; j < 8; j++) d0[j] = sdec[ks * 32 + quad * 8 + j];
        bf16x8 a[4], b[2];
#pragma unroll
        for (int mt = 0; mt < 4; mt++) {
            bf16x8 raw = *(const bf16x8*)(Xb + (size_t)(mt * 16 + l15) * CH + ks * 32 + quad * 8);
#pragma unroll
            for (int j = 0; j < 8; j++) a[mt][j] = (bf16_t)((float)raw[j] * d0[j]);
        }
#pragma unroll
        for (int nt = 0; nt < 2; nt++)
            b[nt] = *(const bf16x8*)(Bb + (size_t)(wave * 32 + nt * 16 + l15) * CH + ks * 32 + quad * 8);
#pragma unroll
        for (int mt = 0; mt < 4; mt++)
#pragma unroll
            for (int nt = 0; nt < 2; nt++)
                acc[mt][nt] = mfma16(a[mt], b[nt], acc[mt][nt]);
    }
#pragma unroll
    for (int mt = 0; mt < 4; mt++)
#pragma unroll
        for (int nt = 0; nt < 2; nt++)
#pragma unroll
            for (int r = 0; r < 4; r++)
                states[(size_t)blk * 64 * DS + (size_t)(mt * 16 + quad * 4 + r) * DS + wave * 32 + nt * 16 + l15] = acc[mt][nt][r];
}

// ---------------- sequential inter-chunk scan ----------------
// grid b*NH = 64 blocks; prev_states[c] emitted BEFORE update (matches lax.scan)
__global__ __launch_bounds__(256) void k_scan(const float* __restrict__ states,
                                              const float* __restrict__ acum,
                                              bf16_t* __restrict__ prevb) {
    int blk = blockIdx.x;  // b*NH + h
    int b = blk >> 5, h = blk & 31;
    int tid = threadIdx.x;
    float prev[32];
#pragma unroll
    for (int j = 0; j < 32; j++) prev[j] = 0.f;
    for (int c = 0; c < NCH; c++) {
        size_t idx = ((size_t)(b * NCH + c) * NH + h);
        size_t base = idx * 64 * DS;
        float dec = expf(acum[idx * CH + CH - 1]);
#pragma unroll
        for (int j = 0; j < 32; j++) {
            size_t i = base + tid + j * 256;
            prevb[i] = (bf16_t)prev[j];
            prev[j] = prev[j] * dec + states[i];
        }
    }
}

// ---------------- fused chunk output: Y = (C B^T ∘ L) Xt^T + (C e^acum) prev^T + D*x ----------------
// grid 1024 = bc*NH+h, 4 waves: wave w -> q rows [w*64, w*64+64)
__global__ __launch_bounds__(256) void k_chunky(const bf16_t* __restrict__ xBC,
                                                const bf16_t* __restrict__ Xt,
                                                const bf16_t* __restrict__ prevb,
                                                const float* __restrict__ acum,
                                                const float* __restrict__ Dp,
                                                bf16_t* __restrict__ yf) {
    int blk = blockIdx.x;
    int bc = blk >> 5, h = blk & 31;
    int tid = threadIdx.x, wave = tid >> 6, lane = tid & 63;
    int l15 = lane & 15, quad = lane >> 4;
    __shared__ __align__(16) float sac[CH];
    __shared__ __align__(16) bf16_t sS[4][64][72];
    sac[tid] = acum[(size_t)blk * CH + tid];
    __syncthreads();

    const bf16_t* Cbase = xBC + (size_t)bc * CH * CD + DI + DS;  // C channels
    const bf16_t* Bbase = xBC + (size_t)bc * CH * CD + DI;       // B channels
    const bf16_t* XtB = Xt + (size_t)blk * 64 * CH;
    const bf16_t* pvB = prevb + (size_t)blk * 64 * DS;

    int qw = wave * 64;
    f32x4 acc[4][4];
#pragma unroll
    for (int i = 0; i < 4; i++)
#pragma unroll
        for (int j = 0; j < 4; j++) acc[i][j] = (f32x4){0.f, 0.f, 0.f, 0.f};

    // ---- Y_off: acc += (C * e^acum[q]) @ prev^T   (K = n = 128); e^acum <= 1, safe
    float ea[4];
#pragma unroll
    for (int mt = 0; mt < 4; mt++) ea[mt] = expf(sac[qw + mt * 16 + l15]);
#pragma unroll
    for (int ks = 0; ks < 4; ks++) {
        bf16x8 a[4], b[4];
#pragma unroll
        for (int mt = 0; mt < 4; mt++) {
            int q = qw + mt * 16 + l15;
            bf16x8 cv = *(const bf16x8*)(Cbase + (size_t)q * CD + ks * 32 + quad * 8);
#pragma unroll
            for (int j = 0; j < 8; j++) a[mt][j] = (bf16_t)((float)cv[j] * ea[mt]);
        }
#pragma unroll
        for (int nt = 0; nt < 4; nt++)
            b[nt] = *(const bf16x8*)(pvB + (size_t)(nt * 16 + l15) * DS + ks * 32 + quad * 8);
#pragma unroll
        for (int mt = 0; mt < 4; mt++)
#pragma unroll
            for (int nt = 0; nt < 4; nt++)
                acc[mt][nt] = mfma16(a[mt], b[nt], acc[mt][nt]);
    }

    // acum for this wave's D-layout rows
    float sacq[4][4];
#pragma unroll
    for (int mt = 0; mt < 4; mt++)
#pragma unroll
        for (int r = 0; r < 4; r++) sacq[mt][r] = sac[qw + mt * 16 + quad * 4 + r];

    // ---- Y_diag over k-tiles of 64; kt > wave is fully masked -> skip
    for (int kt = 0; kt <= wave; kt++) {
        f32x4 s2[4][4];
#pragma unroll
        for (int i = 0; i < 4; i++)
#pragma unroll
            for (int j = 0; j < 4; j++) s2[i][j] = (f32x4){0.f, 0.f, 0.f, 0.f};
        // S = C @ B^T (K = n = 128)
#pragma unroll
        for (int ks = 0; ks < 4; ks++) {
            bf16x8 a[4], b[4];
#pragma unroll
            for (int mt = 0; mt < 4; mt++)
                a[mt] = *(const bf16x8*)(Cbase + (size_t)(qw + mt * 16 + l15) * CD + ks * 32 + quad * 8);
#pragma unroll
            for (int nt = 0; nt < 4; nt++)
                b[nt] = *(const bf16x8*)(Bbase + (size_t)(kt * 64 + nt * 16 + l15) * CD + ks * 32 + quad * 8);
#pragma unroll
            for (int mt = 0; mt < 4; mt++)
#pragma unroll
                for (int nt = 0; nt < 4; nt++)
                    s2[mt][nt] = mfma16(a[mt], b[nt], s2[mt][nt]);
        }
        // apply L = exp(acum[q]-acum[k]) per element (exponent <= 0: NO 0*inf), mask k<=q
        float sack[4];
#pragma unroll
        for (int nt = 0; nt < 4; nt++) sack[nt] = sac[kt * 64 + nt * 16 + l15];
#pragma unroll
        for (int mt = 0; mt < 4; mt++)
#pragma unroll
            for (int nt = 0; nt < 4; nt++) {
                int kp = kt * 64 + nt * 16 + l15;
#pragma unroll
                for (int r = 0; r < 4; r++) {
                    int lq = mt * 16 + quad * 4 + r;
                    int q = qw + lq;
                    float v = (kp <= q) ? s2[mt][nt][r] * __expf(sacq[mt][r] - sack[nt]) : 0.f;
                    sS[wave][lq][nt * 16 + l15] = (bf16_t)v;
                }
            }
        // acc += S~ @ Xt (K = 64, wave-private LDS: no barrier needed)
#pragma unroll
        for (int ks = 0; ks < 2; ks++) {
            bf16x8 a[4], b[4];
#pragma unroll
            for (int mt = 0; mt < 4; mt++)
                a[mt] = *(const bf16x8*)&sS[wave][mt * 16 + l15][ks * 32 + quad * 8];
#pragma unroll
            for (int nt = 0; nt < 4; nt++)
                b[nt] = *(const bf16x8*)(XtB + (size_t)(nt * 16 + l15) * CH + kt * 64 + ks * 32 + quad * 8);
#pragma unroll
            for (int mt = 0; mt < 4; mt++)
#pragma unroll
                for (int nt = 0; nt < 4; nt++)
                    acc[mt][nt] = mfma16(a[mt], b[nt], acc[mt][nt]);
        }
    }

    // ---- epilogue: + D*x, write bf16 y
    float Dh = Dp[h];
#pragma unroll
    for (int mt = 0; mt < 4; mt++)
#pragma unroll
        for (int nt = 0; nt < 4; nt++)
#pragma unroll
            for (int r = 0; r < 4; r++) {
                int q = qw + mt * 16 + quad * 4 + r;
                int p = nt * 16 + l15;
                size_t tok = (size_t)bc * CH + q;
                float xv = (float)xBC[tok * CD + h * 64 + p];
                yf[tok * DI + h * 64 + p] = (bf16_t)(acc[mt][nt][r] + Dh * xv);
            }
}

// ---------------- silu gate + RMS norm -> bf16 ----------------
__global__ __launch_bounds__(256) void k_gate(const bf16_t* __restrict__ yf,
                                              const bf16_t* __restrict__ zb,
                                              const float* __restrict__ nw,
                                              bf16_t* __restrict__ yg) {
    int tok = blockIdx.x, tid = threadIdx.x;
    float g[8];
    float ss = 0.f;
#pragma unroll
    for (int j = 0; j < 8; j++) {
        int d = tid + j * 256;
        float z = (float)zb[(size_t)tok * DI + d];
        float yy = (float)yf[(size_t)tok * DI + d];
        float gg = yy * (z / (1.f + expf(-z)));
        g[j] = gg;
        ss += gg * gg;
    }
#pragma unroll
    for (int off = 32; off > 0; off >>= 1) ss += __shfl_down(ss, off);
    __shared__ __align__(16) float sw[4];
    int wave = tid >> 6, lane = tid & 63;
    if (lane == 0) sw[wave] = ss;
    __syncthreads();
    float tot = sw[0] + sw[1] + sw[2] + sw[3];
    float r = rsqrtf(tot / (float)DI + 1e-5f);
#pragma unroll
    for (int j = 0; j < 8; j++) {
        int d = tid + j * 256;
        yg[(size_t)tok * DI + d] = (bf16_t)(g[j] * r * nw[d]);
    }
}

extern "C" void kernel_launch(void* const* d_in, const int* in_sizes, int n_in,
                              void* d_out, int out_size, void* d_ws, size_t ws_size,
                              hipStream_t stream) {
    const float* u       = (const float*)d_in[0];
    const float* delta_t = (const float*)d_in[1];
    const float* W_in    = (const float*)d_in[2];
    const float* conv_w  = (const float*)d_in[3];
    const float* conv_b  = (const float*)d_in[4];
    const float* dt_bias = (const float*)d_in[5];
    const float* gamma   = (const float*)d_in[6];
    const float* A_log   = (const float*)d_in[7];
    const float* Dp      = (const float*)d_in[8];
    const float* norm_w  = (const float*)d_in[9];
    const float* W_out   = (const float*)d_in[10];
    float* out = (float*)d_out;

    char* p = (char*)d_ws;
    auto alloc = [&](size_t bytes) -> char* {
        char* r = p;
        p += (bytes + 255) & ~(size_t)255;
        return r;
    };
    // total ws use: ~177 MB
    bf16_t* zb_z    = (bf16_t*)alloc((size_t)NTOK * DI * 2);        // 33.5 MB  z (bf16)
    bf16_t* zb_x    = (bf16_t*)alloc((size_t)NTOK * CD * 2);        // 37.75 MB xBC pre-conv; later yf
    bf16_t* Win_bf  = (bf16_t*)alloc((size_t)NP1 * DM * 2);         // 9.2 MB
    bf16_t* Wout_bf = (bf16_t*)alloc((size_t)DM * DI * 2);          // 4.2 MB
    float*  dtb     = (float*)alloc((size_t)NTOK * NH * 4);         // 1 MB
    float*  acum    = (float*)alloc((size_t)NTOK * NH * 4);         // 1 MB
    bf16_t* xBC_bf  = (bf16_t*)alloc((size_t)NTOK * CD * 2);        // 37.75 MB
    bf16_t* Xt      = (bf16_t*)alloc((size_t)NTOK * DI * 2);        // 33.5 MB; later yg
    bf16_t* poolA   = (bf16_t*)alloc((size_t)NTOK * DM * 2);        // 16.8 MB  u_bf then prevb
    bf16_t* Btr     = (bf16_t*)alloc((size_t)BSZ * NCH * DS * CH * 2); // 2.1 MB
    // d_out doubles as scratch: dtf (4.2 MB) then states (33.5 MB), both dead before final GEMM
    float*  dtf     = (float*)d_out;
    float*  states  = (float*)d_out;
    bf16_t* u_bf    = poolA;
    bf16_t* prevb   = poolA;
    bf16_t* yf      = zb_x;
    bf16_t* yg_bf   = Xt;

    k_cvt<<<(NTOK * DM + 255) / 256, 256, 0, stream>>>(u, u_bf, NTOK * DM);
    k_cvt_pad<<<(NP1 * DM + 255) / 256, 256, 0, stream>>>(W_in, Win_bf);
    k_cvt<<<(DM * DI + 255) / 256, 256, 0, stream>>>(W_out, Wout_bf, DM * DI);

    // in-proj split: z (bf16), xBC (bf16), dt (f32, into d_out scratch)
    k_gemm<bf16_t><<<dim3(DI / 128, NTOK / 128), 256, 0, stream>>>(u_bf, Win_bf, zb_z, DM, DI);
    k_gemm<bf16_t><<<dim3(CD / 128, NTOK / 128), 256, 0, stream>>>(u_bf, Win_bf + (size_t)DI * DM, zb_x, DM, CD);
    k_gemm<float><<<dim3(1, NTOK / 128), 256, 0, stream>>>(u_bf, Win_bf + (size_t)(DI + CD) * DM, dtf, DM, 128);

    k_dtcum<<<BSZ * NCH * NH, CH, 0, stream>>>(dtf, delta_t, gamma, dt_bias, A_log, dtb, acum);
    k_conv<<<dim3(CD / 256, NTOK), 256, 0, stream>>>(zb_x, conv_w, conv_b, xBC_bf);
    k_trans<<<dim3(34, BSZ * NCH), 256, 0, stream>>>(xBC_bf, dtb, Xt, Btr);
    k_states<<<BSZ * NCH * NH, 256, 0, stream>>>(Xt, Btr, acum, states);
    k_scan<<<BSZ * NH, 256, 0, stream>>>(states, acum, prevb);
    k_chunky<<<BSZ * NCH * NH, 256, 0, stream>>>(xBC_bf, Xt, prevb, acum, Dp, yf);
    k_gate<<<NTOK, 256, 0, stream>>>(yf, zb_z, norm_w, yg_bf);

    k_gemm<float><<<dim3(DM / 128, NTOK / 128), 256, 0, stream>>>(yg_bf, Wout_bf, out, DI, DM);
}

// Round 3
// 471.336 us; speedup vs baseline: 1.3295x; 1.3295x over previous
//
#include <hip/hip_runtime.h>
#include <hip/hip_bf16.h>
#include <math.h>

// ---- problem constants ----
#define DM    1024      // d_model
#define DIP   4384      // d_in_proj
#define NP1   4480      // padded in_proj rows
#define NPX   4352      // z + xBC columns (combined main GEMM width)
#define DI    2048      // d_inner
#define CD    2304      // conv dim
#define NH    32        // heads
#define HD    64        // head dim
#define DS    128       // d_state
#define CH    256       // chunk
#define NCH   16        // chunks per sequence
#define BSZ   2
#define SEQ   4096
#define NTOK  (BSZ*SEQ) // 8192

typedef __bf16 bf16_t;
typedef __attribute__((ext_vector_type(8))) __bf16 bf16x8;
typedef __attribute__((ext_vector_type(4))) float f32x4;

__device__ __forceinline__ f32x4 mfma16(bf16x8 a, bf16x8 b, f32x4 c) {
    return __builtin_amdgcn_mfma_f32_16x16x32_bf16(a, b, c, 0, 0, 0);
}

__device__ __forceinline__ void gload_lds16(const bf16_t* g, bf16_t* l) {
    __builtin_amdgcn_global_load_lds(
        (const __attribute__((address_space(1))) unsigned int*)g,
        (__attribute__((address_space(3))) unsigned int*)l, 16, 0, 0);
}

// ---------------- converts ----------------
__global__ void k_cvt(const float* __restrict__ in, bf16_t* __restrict__ out, int n) {
    int i = blockIdx.x * 256 + threadIdx.x;
    if (i < n) out[i] = (bf16_t)in[i];
}

__global__ void k_cvt_pad(const float* __restrict__ in, bf16_t* __restrict__ out) {
    int i = blockIdx.x * 256 + threadIdx.x;
    if (i >= NP1 * DM) return;
    int r = i >> 10;  // DM=1024
    out[i] = (r < DIP) ? (bf16_t)in[i] : (bf16_t)0.f;
}

// ---------------- GEMM (m97-style): C[M x ldc] = A[M x K] * Bt[N x K]^T ----------------
// grid (N/128, M/128), block 256 (4 waves, 2x2 of 64x64). global_load_lds width-16 staging,
// unpadded [128][32] LDS (wave-uniform base + lane*16 constraint), 2-barrier K-loop.
template <typename OutT>
__global__ __launch_bounds__(256) void k_gemm(const bf16_t* __restrict__ A,
                                              const bf16_t* __restrict__ Bt,
                                              OutT* __restrict__ C, int K, int ldc) {
    __shared__ __align__(16) bf16_t sA[128 * 32];
    __shared__ __align__(16) bf16_t sB[128 * 32];
    int tid = threadIdx.x, wave = tid >> 6, lane = tid & 63;
    int l15 = lane & 15, quad = lane >> 4;
    int m0 = blockIdx.y * 128, n0 = blockIdx.x * 128;
    int wm = (wave & 1) * 64, wn = (wave >> 1) * 64;
    f32x4 acc[4][4];
#pragma unroll
    for (int i = 0; i < 4; i++)
#pragma unroll
        for (int j = 0; j < 4; j++) acc[i][j] = (f32x4){0.f, 0.f, 0.f, 0.f};

    // staging: wave w covers rows [w*32, w*32+32) in two 16-row issues; lane l -> row +(l>>2), col (l&3)*8
    int srow = lane >> 2, scol = (lane & 3) * 8;
    const bf16_t* Ag0 = A + (size_t)(m0 + wave * 32 + srow) * K + scol;
    const bf16_t* Ag1 = Ag0 + (size_t)16 * K;
    const bf16_t* Bg0 = Bt + (size_t)(n0 + wave * 32 + srow) * K + scol;
    const bf16_t* Bg1 = Bg0 + (size_t)16 * K;
    bf16_t* lA0 = sA + (wave * 32) * 32;
    bf16_t* lA1 = sA + (wave * 32 + 16) * 32;
    bf16_t* lB0 = sB + (wave * 32) * 32;
    bf16_t* lB1 = sB + (wave * 32 + 16) * 32;

    for (int k0 = 0; k0 < K; k0 += 32) {
        gload_lds16(Ag0 + k0, lA0);
        gload_lds16(Ag1 + k0, lA1);
        gload_lds16(Bg0 + k0, lB0);
        gload_lds16(Bg1 + k0, lB1);
        __syncthreads();
        bf16x8 af[4], bg[4];
#pragma unroll
        for (int mt = 0; mt < 4; mt++) af[mt] = *(const bf16x8*)&sA[(wm + mt * 16 + l15) * 32 + quad * 8];
#pragma unroll
        for (int nt = 0; nt < 4; nt++) bg[nt] = *(const bf16x8*)&sB[(wn + nt * 16 + l15) * 32 + quad * 8];
#pragma unroll
        for (int mt = 0; mt < 4; mt++)
#pragma unroll
            for (int nt = 0; nt < 4; nt++)
                acc[mt][nt] = mfma16(af[mt], bg[nt], acc[mt][nt]);
        __syncthreads();
    }
#pragma unroll
    for (int mt = 0; mt < 4; mt++)
#pragma unroll
        for (int nt = 0; nt < 4; nt++)
#pragma unroll
            for (int r = 0; r < 4; r++)
                C[(size_t)(m0 + wm + mt * 16 + quad * 4 + r) * ldc + n0 + wn + nt * 16 + l15] =
                    (OutT)acc[mt][nt][r];
}

// ---------------- dt + softplus + per-chunk cumsum of dt*A ----------------
__global__ __launch_bounds__(256) void k_dtcum(const float* __restrict__ dtf,
                                               const float* __restrict__ delta_t,
                                               const float* __restrict__ gamma,
                                               const float* __restrict__ dt_bias,
                                               const float* __restrict__ A_log,
                                               float* __restrict__ dtb, float* __restrict__ acum) {
    int blk = blockIdx.x;
    int h = blk & (NH - 1), bc = blk >> 5;
    int q = threadIdx.x;
    size_t tok = (size_t)bc * CH + q;
    float x = dtf[tok * 128 + h] + gamma[h] * delta_t[tok] + dt_bias[h];
    float dt = (x > 20.f) ? x : log1pf(expf(x));
    float Ah = -expf(A_log[h]);
    __shared__ __align__(16) float s[CH];
    s[q] = dt * Ah;
    __syncthreads();
#pragma unroll
    for (int off = 1; off < CH; off <<= 1) {
        float v = (q >= off) ? s[q - off] : 0.f;
        __syncthreads();
        s[q] += v;
        __syncthreads();
    }
    dtb[(size_t)blk * CH + q] = dt;
    acum[(size_t)blk * CH + q] = s[q];
}

// ---------------- causal depthwise conv (4 taps) + bias + silu -> bf16 ----------------
// grid (CD/256, NTOK/8): each thread does 8 tokens with register history (11 loads / 8 outputs)
__global__ __launch_bounds__(256) void k_conv(const bf16_t* __restrict__ zxp,
                                              const float* __restrict__ cw,
                                              const float* __restrict__ cb,
                                              bf16_t* __restrict__ xBC) {
    int ch = blockIdx.x * 256 + threadIdx.x;
    int tok0 = blockIdx.y * 8;
    int l0 = tok0 & (SEQ - 1);
    float w0 = cw[ch * 4], w1 = cw[ch * 4 + 1], w2 = cw[ch * 4 + 2], w3 = cw[ch * 4 + 3];
    float bias = cb[ch];
    float h0 = 0.f, h1 = 0.f, h2 = 0.f;
    if (l0 != 0) {
        h0 = (float)zxp[(size_t)(tok0 - 3) * NPX + ch];
        h1 = (float)zxp[(size_t)(tok0 - 2) * NPX + ch];
        h2 = (float)zxp[(size_t)(tok0 - 1) * NPX + ch];
    }
#pragma unroll
    for (int j = 0; j < 8; j++) {
        float cur = (float)zxp[(size_t)(tok0 + j) * NPX + ch];
        float acc = bias + h0 * w0 + h1 * w1 + h2 * w2 + cur * w3;
        float sv = acc / (1.f + expf(-acc));
        xBC[(size_t)(tok0 + j) * CD + ch] = (bf16_t)sv;
        h0 = h1; h1 = h2; h2 = cur;
    }
}

// ---------------- transpose + dt fold ----------------
// grid (34, bc): t<32 -> head t: Xt[p][q] = x*dt ; t in {32,33} -> Btr[n][q]
__global__ __launch_bounds__(256) void k_trans(const bf16_t* __restrict__ xBC,
                                               const float* __restrict__ dtb,
                                               bf16_t* __restrict__ Xt, bf16_t* __restrict__ Btr) {
    int t = blockIdx.x, bc = blockIdx.y, tid = threadIdx.x;
    __shared__ __align__(16) bf16_t tile[CH][72];
    __shared__ __align__(16) float sdt[CH];
    int chbase = (t < 32) ? t * 64 : DI + (t - 32) * 64;
#pragma unroll
    for (int pp = 0; pp < 8; pp++) {
        int q = pp * 32 + (tid >> 3), col = (tid & 7) * 8;
        *(bf16x8*)&tile[q][col] = *(const bf16x8*)(xBC + (size_t)(bc * CH + q) * CD + chbase + col);
    }
    if (t < 32) sdt[tid] = dtb[(size_t)(bc * NH + t) * CH + tid];
    __syncthreads();
    int pl = tid >> 2, qg = tid & 3;
#pragma unroll
    for (int c8 = 0; c8 < 8; c8++) {
        int q0 = qg * 64 + c8 * 8;
        bf16x8 v;
        if (t < 32) {
#pragma unroll
            for (int j = 0; j < 8; j++) v[j] = (bf16_t)((float)tile[q0 + j][pl] * sdt[q0 + j]);
            size_t row = (size_t)(bc * NH + t) * 64 + pl;
            *(bf16x8*)(Xt + row * CH + q0) = v;
        } else {
#pragma unroll
            for (int j = 0; j < 8; j++) v[j] = tile[q0 + j][pl];
            size_t row = (size_t)bc * DS + (t - 32) * 64 + pl;
            *(bf16x8*)(Btr + row * CH + q0) = v;
        }
    }
}

// ---------------- per-chunk states: states[p][n] = sum_k Xt[p][k]*decay[k]*Btr[n][k] ----------------
__global__ __launch_bounds__(256) void k_states(const bf16_t* __restrict__ Xt,
                                                const bf16_t* __restrict__ Btr,
                                                const float* __restrict__ acum,
                                                float* __restrict__ states) {
    int blk = blockIdx.x;
    int bc = blk >> 5;
    int tid = threadIdx.x, wave = tid >> 6, lane = tid & 63;
    int l15 = lane & 15, quad = lane >> 4;
    __shared__ __align__(16) float sdec[CH];
    {
        size_t base = (size_t)blk * CH;
        float al = acum[base + CH - 1];
        sdec[tid] = expf(al - acum[base + tid]);
    }
    __syncthreads();
    const bf16_t* Xb = Xt + (size_t)blk * 64 * CH;
    const bf16_t* Bb = Btr + (size_t)bc * DS * CH;
    f32x4 acc[4][2];
#pragma unroll
    for (int i = 0; i < 4; i++)
#pragma unroll
        for (int j = 0; j < 2; j++) acc[i][j] = (f32x4){0.f, 0.f, 0.f, 0.f};
#pragma unroll
    for (int ks = 0; ks < 8; ks++) {
        float d0[8];
#pragma unroll
        for (int j = 0; j < 8; j++) d0[j] = sdec[ks * 32 + quad * 8 + j];
        bf16x8 a[4], b[2];
#pragma unroll
        for (int mt = 0; mt < 4; mt++) {
            bf16x8 raw = *(const bf16x8*)(Xb + (size_t)(mt * 16 + l15) * CH + ks * 32 + quad * 8);
#pragma unroll
            for (int j = 0; j < 8; j++) a[mt][j] = (bf16_t)((float)raw[j] * d0[j]);
        }
#pragma unroll
        for (int nt = 0; nt < 2; nt++)
            b[nt] = *(const bf16x8*)(Bb + (size_t)(wave * 32 + nt * 16 + l15) * CH + ks * 32 + quad * 8);
#pragma unroll
        for (int mt = 0; mt < 4; mt++)
#pragma unroll
            for (int nt = 0; nt < 2; nt++)
                acc[mt][nt] = mfma16(a[mt], b[nt], acc[mt][nt]);
    }
#pragma unroll
    for (int mt = 0; mt < 4; mt++)
#pragma unroll
        for (int nt = 0; nt < 2; nt++)
#pragma unroll
            for (int r = 0; r < 4; r++)
                states[(size_t)blk * 64 * DS + (size_t)(mt * 16 + quad * 4 + r) * DS + wave * 32 + nt * 16 + l15] = acc[mt][nt][r];
}

// ---------------- parallel inter-chunk scan: grid BSZ*NH*32, 256 thr, 1 elem/thread ----------------
__global__ __launch_bounds__(256) void k_scan(const float* __restrict__ states,
                                              const float* __restrict__ acum,
                                              bf16_t* __restrict__ prevb) {
    int blk = blockIdx.x;
    int bh = blk >> 5;         // b*NH + h
    int b = bh >> 5, h = bh & 31;
    int e = (blk & 31) * 256 + threadIdx.x;  // element within 64*128
    float prev = 0.f;
    for (int c = 0; c < NCH; c++) {
        size_t idx = (size_t)(b * NCH + c) * NH + h;
        float dec = expf(acum[idx * CH + CH - 1]);
        size_t i = idx * 64 * DS + e;
        prevb[i] = (bf16_t)prev;
        prev = prev * dec + states[i];
    }
}

// ---------------- Sraw generator: 6 off-diagonal 64x64 tiles of S = C @ B^T per chunk ----------------
// grid (6, 32 chunks), 4 waves: wave w -> q rows [w*16, w*16+16)
__global__ __launch_bounds__(256) void k_sgen(const bf16_t* __restrict__ xBC,
                                              bf16_t* __restrict__ Sraw) {
    int t = blockIdx.x, bc = blockIdx.y;
    int qt = (t == 0) ? 1 : (t < 3) ? 2 : 3;
    int kt = t - qt * (qt - 1) / 2;
    int tid = threadIdx.x, wave = tid >> 6, lane = tid & 63;
    int l15 = lane & 15, quad = lane >> 4;
    const bf16_t* Cbase = xBC + (size_t)bc * CH * CD + DI + DS;
    const bf16_t* Bbase = xBC + (size_t)bc * CH * CD + DI;
    f32x4 acc[4];
#pragma unroll
    for (int j = 0; j < 4; j++) acc[j] = (f32x4){0.f, 0.f, 0.f, 0.f};
#pragma unroll
    for (int ks = 0; ks < 4; ks++) {
        bf16x8 a = *(const bf16x8*)(Cbase + (size_t)(qt * 64 + wave * 16 + l15) * CD + ks * 32 + quad * 8);
        bf16x8 b[4];
#pragma unroll
        for (int nt = 0; nt < 4; nt++)
            b[nt] = *(const bf16x8*)(Bbase + (size_t)(kt * 64 + nt * 16 + l15) * CD + ks * 32 + quad * 8);
#pragma unroll
        for (int nt = 0; nt < 4; nt++) acc[nt] = mfma16(a, b[nt], acc[nt]);
    }
    bf16_t* out = Sraw + ((size_t)bc * 6 + t) * 64 * 64;
#pragma unroll
    for (int nt = 0; nt < 4; nt++)
#pragma unroll
        for (int r = 0; r < 4; r++)
            out[(size_t)(wave * 16 + quad * 4 + r) * 64 + nt * 16 + l15] = (bf16_t)acc[nt][r];
}

// ---------------- fused chunk output ----------------
// Y = eq[q] * ( s_ref * C@prev^T  +  sum_{kt<qt} Sraw_t @ (Xt*ek)^T )  +  diag-tile  + D*x
// grid 1024 = bc*NH+h, wave w = q-tile w
__global__ __launch_bounds__(256) void k_chunky(const bf16_t* __restrict__ xBC,
                                                const bf16_t* __restrict__ Xt,
                                                const bf16_t* __restrict__ prevb,
                                                const bf16_t* __restrict__ Sraw,
                                                const float* __restrict__ acum,
                                                const float* __restrict__ Dp,
                                                bf16_t* __restrict__ yf) {
    int blk = blockIdx.x;
    int bc = blk >> 5, h = blk & 31;
    int tid = threadIdx.x, wave = tid >> 6, lane = tid & 63;
    int l15 = lane & 15, quad = lane >> 4;
    __shared__ __align__(16) float sac[CH];
    __shared__ __align__(16) bf16_t sS[4][64][72];
    sac[tid] = acum[(size_t)blk * CH + tid];
    __syncthreads();

    const bf16_t* Cbase = xBC + (size_t)bc * CH * CD + DI + DS;
    const bf16_t* Bbase = xBC + (size_t)bc * CH * CD + DI;
    const bf16_t* XtB = Xt + (size_t)blk * 64 * CH;
    const bf16_t* pvB = prevb + (size_t)blk * 64 * DS;

    int qw = wave * 64;
    float refq = sac[qw];          // q-tile reference
    float s_ref = expf(refq);      // <= 1
    f32x4 acc[4][4];
#pragma unroll
    for (int i = 0; i < 4; i++)
#pragma unroll
        for (int j = 0; j < 4; j++) acc[i][j] = (f32x4){0.f, 0.f, 0.f, 0.f};

    // ---- Y_off: acc = C @ prev^T (unscaled), then *= s_ref
#pragma unroll
    for (int ks = 0; ks < 4; ks++) {
        bf16x8 a[4], b[4];
#pragma unroll
        for (int mt = 0; mt < 4; mt++)
            a[mt] = *(const bf16x8*)(Cbase + (size_t)(qw + mt * 16 + l15) * CD + ks * 32 + quad * 8);
#pragma unroll
        for (int nt = 0; nt < 4; nt++)
            b[nt] = *(const bf16x8*)(pvB + (size_t)(nt * 16 + l15) * DS + ks * 32 + quad * 8);
#pragma unroll
        for (int mt = 0; mt < 4; mt++)
#pragma unroll
            for (int nt = 0; nt < 4; nt++)
                acc[mt][nt] = mfma16(a[mt], b[nt], acc[mt][nt]);
    }
#pragma unroll
    for (int mt = 0; mt < 4; mt++)
#pragma unroll
        for (int nt = 0; nt < 4; nt++)
#pragma unroll
            for (int r = 0; r < 4; r++) acc[mt][nt][r] *= s_ref;

    // ---- off-diagonal tiles: acc += Sraw @ (Xt * ek)^T
    for (int kt = 0; kt < wave; kt++) {
        const bf16_t* St = Sraw + ((size_t)bc * 6 + wave * (wave - 1) / 2 + kt) * 64 * 64;
#pragma unroll
        for (int ks = 0; ks < 2; ks++) {
            float ekv[8];
#pragma unroll
            for (int j = 0; j < 8; j++)
                ekv[j] = __expf(refq - sac[kt * 64 + ks * 32 + quad * 8 + j]);
            bf16x8 a[4], b[4];
#pragma unroll
            for (int mt = 0; mt < 4; mt++)
                a[mt] = *(const bf16x8*)(St + (size_t)(mt * 16 + l15) * 64 + ks * 32 + quad * 8);
#pragma unroll
            for (int nt = 0; nt < 4; nt++) {
                bf16x8 raw = *(const bf16x8*)(XtB + (size_t)(nt * 16 + l15) * CH + kt * 64 + ks * 32 + quad * 8);
#pragma unroll
                for (int j = 0; j < 8; j++) b[nt][j] = (bf16_t)((float)raw[j] * ekv[j]);
            }
#pragma unroll
            for (int mt = 0; mt < 4; mt++)
#pragma unroll
                for (int nt = 0; nt < 4; nt++)
                    acc[mt][nt] = mfma16(a[mt], b[nt], acc[mt][nt]);
        }
    }

    // ---- epilogue scaling by eq[q] = exp(acum[q] - refq)  (D-layout rows)
    float sacq[4][4];
#pragma unroll
    for (int mt = 0; mt < 4; mt++)
#pragma unroll
        for (int r = 0; r < 4; r++) sacq[mt][r] = sac[qw + mt * 16 + quad * 4 + r];
#pragma unroll
    for (int mt = 0; mt < 4; mt++) {
        float eqv[4];
#pragma unroll
        for (int r = 0; r < 4; r++) eqv[r] = __expf(sacq[mt][r] - refq);
#pragma unroll
        for (int nt = 0; nt < 4; nt++)
#pragma unroll
            for (int r = 0; r < 4; r++) acc[mt][nt][r] *= eqv[r];
    }

    // ---- diagonal tile (kt = wave): per-element L, LDS round-trip
    {
        int kt = wave;
        f32x4 s2[4][4];
#pragma unroll
        for (int i = 0; i < 4; i++)
#pragma unroll
            for (int j = 0; j < 4; j++) s2[i][j] = (f32x4){0.f, 0.f, 0.f, 0.f};
#pragma unroll
        for (int ks = 0; ks < 4; ks++) {
            bf16x8 a[4], b[4];
#pragma unroll
            for (int mt = 0; mt < 4; mt++)
                a[mt] = *(const bf16x8*)(Cbase + (size_t)(qw + mt * 16 + l15) * CD + ks * 32 + quad * 8);
#pragma unroll
            for (int nt = 0; nt < 4; nt++)
                b[nt] = *(const bf16x8*)(Bbase + (size_t)(kt * 64 + nt * 16 + l15) * CD + ks * 32 + quad * 8);
#pragma unroll
            for (int mt = 0; mt < 4; mt++)
#pragma unroll
                for (int nt = 0; nt < 4; nt++)
                    s2[mt][nt] = mfma16(a[mt], b[nt], s2[mt][nt]);
        }
        float sack[4];
#pragma unroll
        for (int nt = 0; nt < 4; nt++) sack[nt] = sac[kt * 64 + nt * 16 + l15];
#pragma unroll
        for (int mt = 0; mt < 4; mt++)
#pragma unroll
            for (int nt = 0; nt < 4; nt++) {
                int kp = kt * 64 + nt * 16 + l15;
#pragma unroll
                for (int r = 0; r < 4; r++) {
                    int lq = mt * 16 + quad * 4 + r;
                    int q = qw + lq;
                    float v = (kp <= q) ? s2[mt][nt][r] * __expf(sacq[mt][r] - sack[nt]) : 0.f;
                    sS[wave][lq][nt * 16 + l15] = (bf16_t)v;
                }
            }
#pragma unroll
        for (int ks = 0; ks < 2; ks++) {
            bf16x8 a[4], b[4];
#pragma unroll
            for (int mt = 0; mt < 4; mt++)
                a[mt] = *(const bf16x8*)&sS[wave][mt * 16 + l15][ks * 32 + quad * 8];
#pragma unroll
            for (int nt = 0; nt < 4; nt++)
                b[nt] = *(const bf16x8*)(XtB + (size_t)(nt * 16 + l15) * CH + kt * 64 + ks * 32 + quad * 8);
#pragma unroll
            for (int mt = 0; mt < 4; mt++)
#pragma unroll
                for (int nt = 0; nt < 4; nt++)
                    acc[mt][nt] = mfma16(a[mt], b[nt], acc[mt][nt]);
        }
    }

    // ---- epilogue: + D*x, write bf16 y
    float Dh = Dp[h];
#pragma unroll
    for (int mt = 0; mt < 4; mt++)
#pragma unroll
        for (int nt = 0; nt < 4; nt++)
#pragma unroll
            for (int r = 0; r < 4; r++) {
                int q = qw + mt * 16 + quad * 4 + r;
                int p = nt * 16 + l15;
                size_t tok = (size_t)bc * CH + q;
                float xv = (float)xBC[tok * CD + h * 64 + p];
                yf[tok * DI + h * 64 + p] = (bf16_t)(acc[mt][nt][r] + Dh * xv);
            }
}

// ---------------- silu gate + RMS norm -> bf16 ----------------
__global__ __launch_bounds__(256) void k_gate(const bf16_t* __restrict__ yf,
                                              const bf16_t* __restrict__ zb,
                                              const float* __restrict__ nw,
                                              bf16_t* __restrict__ yg) {
    int tok = blockIdx.x, tid = threadIdx.x;
    float g[8];
    float ss = 0.f;
#pragma unroll
    for (int j = 0; j < 8; j++) {
        int d = tid + j * 256;
        float z = (float)zb[(size_t)tok * NPX + d];
        float yy = (float)yf[(size_t)tok * DI + d];
        float gg = yy * (z / (1.f + expf(-z)));
        g[j] = gg;
        ss += gg * gg;
    }
#pragma unroll
    for (int off = 32; off > 0; off >>= 1) ss += __shfl_down(ss, off);
    __shared__ __align__(16) float sw[4];
    int wave = tid >> 6, lane = tid & 63;
    if (lane == 0) sw[wave] = ss;
    __syncthreads();
    float tot = sw[0] + sw[1] + sw[2] + sw[3];
    float r = rsqrtf(tot / (float)DI + 1e-5f);
#pragma unroll
    for (int j = 0; j < 8; j++) {
        int d = tid + j * 256;
        yg[(size_t)tok * DI + d] = (bf16_t)(g[j] * r * nw[d]);
    }
}

extern "C" void kernel_launch(void* const* d_in, const int* in_sizes, int n_in,
                              void* d_out, int out_size, void* d_ws, size_t ws_size,
                              hipStream_t stream) {
    const float* u       = (const float*)d_in[0];
    const float* delta_t = (const float*)d_in[1];
    const float* W_in    = (const float*)d_in[2];
    const float* conv_w  = (const float*)d_in[3];
    const float* conv_b  = (const float*)d_in[4];
    const float* dt_bias = (const float*)d_in[5];
    const float* gamma   = (const float*)d_in[6];
    const float* A_log   = (const float*)d_in[7];
    const float* Dp      = (const float*)d_in[8];
    const float* norm_w  = (const float*)d_in[9];
    const float* W_out   = (const float*)d_in[10];
    float* out = (float*)d_out;

    char* p = (char*)d_ws;
    auto alloc = [&](size_t bytes) -> char* {
        char* r = p;
        p += (bytes + 255) & ~(size_t)255;
        return r;
    };
    // ~179 MB total
    bf16_t* zxBC    = (bf16_t*)alloc((size_t)NTOK * NPX * 2);          // 71.3 MB  z | xBC pre-conv
    bf16_t* Win_bf  = (bf16_t*)alloc((size_t)NP1 * DM * 2);            // 9.2 MB
    bf16_t* Wout_bf = (bf16_t*)alloc((size_t)DM * DI * 2);             // 4.2 MB
    float*  dtb     = (float*)alloc((size_t)NTOK * NH * 4);            // 1 MB
    float*  acum    = (float*)alloc((size_t)NTOK * NH * 4);            // 1 MB
    bf16_t* xBC_bf  = (bf16_t*)alloc((size_t)NTOK * CD * 2);           // 37.75 MB
    bf16_t* Xt      = (bf16_t*)alloc((size_t)NTOK * DI * 2);           // 33.5 MB; later yg
    bf16_t* poolA   = (bf16_t*)alloc((size_t)NTOK * DM * 2);           // 16.8 MB  u_bf then prevb
    bf16_t* Btr     = (bf16_t*)alloc((size_t)BSZ * NCH * DS * CH * 2); // 2.1 MB
    bf16_t* Sraw    = (bf16_t*)alloc((size_t)BSZ * NCH * 6 * 64 * 64 * 2); // 1.5 MB
    // d_out scratch phases: dtf -> states -> yf -> out
    float*  dtf     = (float*)d_out;
    float*  states  = (float*)d_out;
    bf16_t* yf      = (bf16_t*)d_out;
    bf16_t* u_bf    = poolA;
    bf16_t* prevb   = poolA;
    bf16_t* yg_bf   = Xt;

    k_cvt<<<(NTOK * DM + 255) / 256, 256, 0, stream>>>(u, u_bf, NTOK * DM);
    k_cvt_pad<<<(NP1 * DM + 255) / 256, 256, 0, stream>>>(W_in, Win_bf);
    k_cvt<<<(DM * DI + 255) / 256, 256, 0, stream>>>(W_out, Wout_bf, DM * DI);

    // in-proj: combined z+xBC (bf16) and dt (f32, d_out scratch)
    k_gemm<bf16_t><<<dim3(NPX / 128, NTOK / 128), 256, 0, stream>>>(u_bf, Win_bf, zxBC, DM, NPX);
    k_gemm<float><<<dim3(1, NTOK / 128), 256, 0, stream>>>(u_bf, Win_bf + (size_t)NPX * DM, dtf, DM, 128);

    k_dtcum<<<BSZ * NCH * NH, CH, 0, stream>>>(dtf, delta_t, gamma, dt_bias, A_log, dtb, acum);
    k_conv<<<dim3(CD / 256, NTOK / 8), 256, 0, stream>>>(zxBC + DI, conv_w, conv_b, xBC_bf);
    k_sgen<<<dim3(6, BSZ * NCH), 256, 0, stream>>>(xBC_bf, Sraw);
    k_trans<<<dim3(34, BSZ * NCH), 256, 0, stream>>>(xBC_bf, dtb, Xt, Btr);
    k_states<<<BSZ * NCH * NH, 256, 0, stream>>>(Xt, Btr, acum, states);
    k_scan<<<BSZ * NH * 32, 256, 0, stream>>>(states, acum, prevb);
    k_chunky<<<BSZ * NCH * NH, 256, 0, stream>>>(xBC_bf, Xt, prevb, Sraw, acum, Dp, yf);
    k_gate<<<NTOK, 256, 0, stream>>>(yf, zxBC, norm_w, yg_bf);

    k_gemm<float><<<dim3(DM / 128, NTOK / 128), 256, 0, stream>>>(yg_bf, Wout_bf, out, DI, DM);
}